// Round 2
// baseline (275.178 us; speedup 1.0000x reference)
//
#include <hip/hip_runtime.h>
#include <stdint.h>

typedef __attribute__((ext_vector_type(8))) short short8;
typedef __attribute__((ext_vector_type(4))) float f32x4;
typedef __attribute__((ext_vector_type(4))) float float4v;
typedef __attribute__((ext_vector_type(2))) unsigned short u16x2;
typedef __attribute__((ext_vector_type(4))) unsigned short u16x4;
typedef __attribute__((ext_vector_type(8))) unsigned short u16x8;

#define AS1 __attribute__((address_space(1)))
#define AS3 __attribute__((address_space(3)))

// B=4, C=512, Lf=8192, A=6. N = 49152.
// d_out: obj [4][49152] @0, reg [4][49152][2] @196608, anchors [49152][2] @589824.
// ws layout (bytes):
//   wAf   @ 0        : bf16 pre-fragmented conv weights, chunk id =
//                      (cb*3+t)*16+kc, 512 elems/chunk, lane i of chunk holds
//                      A[cout=cb*16+(i&15)][cin=kc*32+(i>>4)*8 .. +8]  (1,572,864)
//   hwp   @ 1572864  : bf16 [32][512], rows 0-5 obj_w, 6-17 reg_w, rest 0 (32,768)
//   featT @ 1605632  : bf16 [4][8208][512], row r holds l=r-1;
//                      rows 0 and 8193 zeroed (SAME pad), 8194+ slop (33,619,968)
//   part  @ 35225600 : fp32 [4 mblk][4 b][8192 l][18 j] head partials (9,437,184)

__device__ __forceinline__ unsigned short f2bf(float f) {
    union { float f; unsigned int u; } v; v.f = f;
    unsigned int r = v.u + 0x7fffu + ((v.u >> 16) & 1u);
    return (unsigned short)(r >> 16);
}

__constant__ float c_AL[6] = {2.f, 4.f, 6.f, 9.f, 13.f, 18.f};

// blocks [0,4096): 64x64 transpose tiles.  blocks [4096,7440): prep work.
// Transpose tile is [c][l] stride 66: writes are u16x2 (free), reads are
// paired ds_read_b32 (lane gets l,l+1 of one c) hitting all 32 banks
// (bank = 8*(c8%4)+j+lp, 2-way = free), then register repack to u16x8 rows.
__global__ __launch_bounds__(256) void prep_transpose_kernel(
    const float* __restrict__ feat, const float* __restrict__ conv_w,
    const float* __restrict__ obj_w, const float* __restrict__ reg_w,
    unsigned short* __restrict__ wAf, unsigned short* __restrict__ hwp,
    unsigned short* __restrict__ featT, float* __restrict__ out) {
    __shared__ unsigned short tile[64][66];   // bf16 [c][l], stride 66
    unsigned int bx = blockIdx.x;
    int tid = threadIdx.x;
    if (bx < 4096u) {
        int l0 = (bx & 127) * 64, c0 = ((bx >> 7) & 7) * 64, b = bx >> 10;
        const float* fb = feat + ((size_t)b * 512 + c0) * 8192 + l0;
        #pragma unroll
        for (int it = 0; it < 4; ++it) {
            int slot = it * 256 + tid;
            int c = slot >> 4, l4 = (slot & 15) << 2;
            float4v v = *(const float4v*)(fb + (size_t)c * 8192 + l4);
            u16x2 p0, p1;
            p0.x = f2bf(v.x); p0.y = f2bf(v.y);
            p1.x = f2bf(v.z); p1.y = f2bf(v.w);
            *(u16x2*)(&tile[c][l4])     = p0;
            *(u16x2*)(&tile[c][l4 + 2]) = p1;
        }
        __syncthreads();
        unsigned short* ftb = featT + ((size_t)b * 8208 + 1 + l0) * 512 + c0;
        int c8 = tid & 7, lp = tid >> 3;          // c-chunk 0..7, l-pair 0..31
        unsigned int w[8];
        #pragma unroll
        for (int j = 0; j < 8; ++j)
            w[j] = *(const unsigned int*)(&tile[c8 * 8 + j][lp * 2]);
        u16x8 lo, hi;
        #pragma unroll
        for (int d = 0; d < 4; ++d) {
            unsigned int a = w[2 * d], bb = w[2 * d + 1];
            ((unsigned int*)&lo)[d] = (a & 0xffffu) | (bb << 16);
            ((unsigned int*)&hi)[d] = (a >> 16) | (bb & 0xffff0000u);
        }
        *(u16x8*)(ftb + (size_t)(lp * 2) * 512 + c8 * 8)     = lo;
        *(u16x8*)(ftb + (size_t)(lp * 2 + 1) * 512 + c8 * 8) = hi;
        return;
    }
    unsigned int idx = (bx - 4096u) * 256 + tid;
    if (idx < 786432u) {
        // fragment-major conv weights
        unsigned int chunkid = idx >> 9;            // 0..1535
        unsigned int within = idx & 511u;
        unsigned int lane = within >> 3, j = within & 7u;
        unsigned int kc = chunkid & 15u;
        unsigned int ct = chunkid >> 4;             // cb*3 + t
        unsigned int t = ct % 3u, cb = ct / 3u;
        unsigned int cout = cb * 16u + (lane & 15u);
        unsigned int cin = kc * 32u + (lane >> 4) * 8u + j;
        wAf[idx] = f2bf(conv_w[(cout * 512u + cin) * 3u + t]);
    } else if (idx < 802816u) {
        unsigned int i2 = idx - 786432u;
        unsigned int j = i2 >> 9, c = i2 & 511u;
        float v = 0.f;
        if (j < 6u) v = obj_w[j * 512u + c];
        else if (j < 18u) v = reg_w[(j - 6u) * 512u + c];
        hwp[i2] = f2bf(v);
    } else if (idx < 851968u) {
        unsigned int n = idx - 802816u;
        unsigned int l = n / 6u, a = n - l * 6u;
        float ctr = (float)l + 0.5f, half = 0.5f * c_AL[a];
        float* anchors = out + 589824;
        anchors[2 * n]     = ctr - half;
        anchors[2 * n + 1] = ctr + half;
    } else if (idx < 856064u) {
        unsigned int i4 = idx - 851968u;
        unsigned int b = i4 >> 10, rem = i4 & 1023u;
        unsigned int row = (rem >> 9) ? 8193u : 0u;
        unsigned int c = rem & 511u;
        featT[((size_t)b * 8208 + row) * 512 + c] = 0;
    }
}

// Conv GEMM: per block, 128 couts x 128 l's, K = 3 taps * 512 cin.
// Schedule: 48 phases (kc 0..15 x tap 0..2).  A is double-buffered per
// tap-phase (2 x 8 chunks), B per kc (2 x 9 chunks) — 34,816 B total,
// 4 blocks/CU.  Each phase issues next-phase staging (global_load_lds,
// 2 A + <=1 B per wave), then a COUNTED s_waitcnt vmcnt(3/2) (never 0
// mid-loop: this phase's loads stay in flight across the barrier and
// land under the MFMA cluster), barrier, conflict-free fragment-major
// ds_read_b128, setprio-wrapped 16 MFMA, barrier.  Epilogue unchanged:
// bias+relu -> bf16 htile, fused heads mini-GEMM -> per-mblock partials.
__global__ __launch_bounds__(256, 4) void conv_gemm_kernel(
    const unsigned short* __restrict__ wAf,
    const unsigned short* __restrict__ featT,
    const float* __restrict__ conv_b,
    const unsigned short* __restrict__ hwp,
    float* __restrict__ part) {
    __shared__ unsigned short smem[17408];  // A: 2x4096 @0, B: 2x4608 @8192; epi htile 128*136

    const int tid = threadIdx.x;
    const int wave = tid >> 6, lane = tid & 63;
    const int lq = lane >> 4, lr = lane & 15;
    const int l0 = blockIdx.x * 128;
    const int m0 = blockIdx.y * 128;
    const int b = blockIdx.z;
    const int wm = wave >> 1, wn = wave & 1;
    const unsigned short* ftb = featT + (size_t)b * 8208 * 512;

    unsigned short* Ab0 = smem;
    unsigned short* Ab1 = smem + 4096;
    unsigned short* Bb0 = smem + 8192;
    unsigned short* Bb1 = smem + 8192 + 4608;

    auto stageA = [&](int rb, int tt, int kk, unsigned short* dst) {
        const unsigned short* g =
            wAf + ((size_t)((((m0 >> 4) + rb) * 3 + tt) * 16 + kk)) * 512 + lane * 8;
        __builtin_amdgcn_global_load_lds((const AS1 void*)g,
                                         (AS3 void*)(dst + rb * 512), 16, 0, 0);
    };
    auto stageB = [&](int cb, int kk, unsigned short* dst) {
        const unsigned short* g =
            ftb + (size_t)(l0 + cb * 16 + lr) * 512 + kk * 32 + lq * 8;
        __builtin_amdgcn_global_load_lds((const AS1 void*)g,
                                         (AS3 void*)(dst + cb * 512), 16, 0, 0);
    };

    f32x4 acc[4][4];
    #pragma unroll
    for (int i = 0; i < 4; ++i)
        #pragma unroll
        for (int j = 0; j < 4; ++j)
            acc[i][j] = (f32x4){0.f, 0.f, 0.f, 0.f};

    // prologue: A for phase 0 (8 chunks), B for kc 0 (9 chunks)
    stageA(wave, 0, 0, Ab0);
    stageA(wave + 4, 0, 0, Ab0);
    stageB(wave, 0, Bb0);
    stageB(wave + 4, 0, Bb0);
    if (wave == 0) stageB(8, 0, Bb0);

    for (int kc = 0; kc < 16; ++kc) {
        unsigned short* Bcur = (kc & 1) ? Bb1 : Bb0;
        unsigned short* Bnxt = (kc & 1) ? Bb0 : Bb1;
        #pragma unroll
        for (int t = 0; t < 3; ++t) {
            const int p = kc * 3 + t;
            unsigned short* Acur = (p & 1) ? Ab1 : Ab0;
            unsigned short* Anxt = (p & 1) ? Ab0 : Ab1;
            // ---- issue staging for phase p+1 (lands under this phase's MFMA)
            if (kc < 15 || t < 2) {
                const int kcn = (t == 2) ? kc + 1 : kc;
                const int tn  = (t == 2) ? 0 : t + 1;
                stageA(wave, tn, kcn, Anxt);
                stageA(wave + 4, tn, kcn, Anxt);
                if (kc < 15 && wave < 3) stageB(3 * t + wave, kc + 1, Bnxt);
            }
            // ---- counted wait: drain phase p-1's loads, keep phase p's in flight
            if (kc < 15) {
                if (wave < 3) asm volatile("s_waitcnt vmcnt(3)" ::: "memory");
                else          asm volatile("s_waitcnt vmcnt(2)" ::: "memory");
            } else {
                if (t < 2) asm volatile("s_waitcnt vmcnt(2)" ::: "memory");
                else       asm volatile("s_waitcnt vmcnt(0)" ::: "memory");
            }
            __builtin_amdgcn_s_barrier();
            asm volatile("" ::: "memory");
            short8 af[4], bf[4];
            #pragma unroll
            for (int fm = 0; fm < 4; ++fm)
                af[fm] = *(const short8*)(Acur + ((wm * 4 + fm) << 9) + (lane << 3));
            #pragma unroll
            for (int fn = 0; fn < 4; ++fn) {
                int R = wn * 64 + fn * 16 + lr + t;   // tap-shifted B row
                bf[fn] = *(const short8*)(Bcur + ((R >> 4) << 9) +
                                          ((((lq << 4) | (R & 15))) << 3));
            }
            __builtin_amdgcn_s_setprio(1);
            #pragma unroll
            for (int fm = 0; fm < 4; ++fm)
                #pragma unroll
                for (int fn = 0; fn < 4; ++fn)
                    acc[fm][fn] = __builtin_amdgcn_mfma_f32_16x16x32_bf16(
                        af[fm], bf[fn], acc[fm][fn], 0, 0, 0);
            __builtin_amdgcn_s_setprio(0);
            __builtin_amdgcn_s_barrier();   // reads of p done before p+1 overwrite
            asm volatile("" ::: "memory");
        }
    }
    __syncthreads();
    // epilogue 1: bias + relu -> bf16 htile [l=n][c=cout], row stride 136
    #pragma unroll
    for (int fm = 0; fm < 4; ++fm) {
        int mb = wm * 64 + fm * 16 + lq * 4;
        float cb0 = conv_b[m0 + mb];
        float cb1 = conv_b[m0 + mb + 1];
        float cb2 = conv_b[m0 + mb + 2];
        float cb3 = conv_b[m0 + mb + 3];
        #pragma unroll
        for (int fn = 0; fn < 4; ++fn) {
            int n = wn * 64 + fn * 16 + lr;
            f32x4 v = acc[fm][fn];
            u16x4 pk;
            pk.x = f2bf(fmaxf(v.x + cb0, 0.f));
            pk.y = f2bf(fmaxf(v.y + cb1, 0.f));
            pk.z = f2bf(fmaxf(v.z + cb2, 0.f));
            pk.w = f2bf(fmaxf(v.w + cb3, 0.f));
            *(u16x4*)(smem + n * 136 + mb) = pk;
        }
    }
    __syncthreads();
    // epilogue 2: fused heads. Per wave: 32 l's x 32 j's x K=128 local couts.
    f32x4 hacc[2][2];
    #pragma unroll
    for (int i = 0; i < 2; ++i) {
        hacc[i][0] = (f32x4){0.f, 0.f, 0.f, 0.f};
        hacc[i][1] = (f32x4){0.f, 0.f, 0.f, 0.f};
    }
    const int lbase = wave * 32;
    for (int kk = 0; kk < 4; ++kk) {
        short8 ha[2], hb2[2];
        #pragma unroll
        for (int fm2 = 0; fm2 < 2; ++fm2)
            ha[fm2] = *(const short8*)(smem + (lbase + fm2 * 16 + lr) * 136 + kk * 32 + lq * 8);
        #pragma unroll
        for (int fn = 0; fn < 2; ++fn)
            hb2[fn] = *(const short8*)(hwp + (size_t)(fn * 16 + lr) * 512 + m0 + kk * 32 + lq * 8);
        #pragma unroll
        for (int fm2 = 0; fm2 < 2; ++fm2)
            #pragma unroll
            for (int fn = 0; fn < 2; ++fn)
                hacc[fm2][fn] = __builtin_amdgcn_mfma_f32_16x16x32_bf16(
                    ha[fm2], hb2[fn], hacc[fm2][fn], 0, 0, 0);
    }
    // partials store: part[mblk=by][b][l][j]
    float* pb = part + ((size_t)(blockIdx.y * 4 + b) * 8192) * 18;
    #pragma unroll
    for (int fn = 0; fn < 2; ++fn) {
        int j = fn * 16 + lr;
        if (j >= 18) continue;
        #pragma unroll
        for (int fm2 = 0; fm2 < 2; ++fm2)
            #pragma unroll
            for (int r = 0; r < 4; ++r) {
                int l = l0 + lbase + fm2 * 16 + lq * 4 + r;
                pb[(size_t)l * 18 + j] = hacc[fm2][fn][r];
            }
    }
}

__global__ __launch_bounds__(256) void reduce_kernel(
    const float* __restrict__ part, const float* __restrict__ obj_b,
    const float* __restrict__ reg_b, float* __restrict__ out) {
    unsigned int idx = blockIdx.x * 256 + threadIdx.x;
    if (idx >= 589824u) return;
    unsigned int j = idx % 18u;
    unsigned int t = idx / 18u;
    unsigned int l = t & 8191u;
    unsigned int b = t >> 13;
    float s = 0.f;
    #pragma unroll
    for (int mb = 0; mb < 4; ++mb)
        s += part[((size_t)(mb * 4 + b) * 8192 + l) * 18 + j];
    if (j < 6u) {
        s += obj_b[j];
        out[(size_t)b * 49152 + l * 6 + j] = s;
    } else {
        s += reg_b[j - 6u];
        out[196608u + (size_t)b * 98304 + l * 12 + (j - 6u)] = s;
    }
}

extern "C" void kernel_launch(void* const* d_in, const int* in_sizes, int n_in,
                              void* d_out, int out_size, void* d_ws, size_t ws_size,
                              hipStream_t stream) {
    const float* feat   = (const float*)d_in[0];
    const float* conv_w = (const float*)d_in[1];
    const float* conv_b = (const float*)d_in[2];
    const float* obj_w  = (const float*)d_in[3];
    const float* obj_b  = (const float*)d_in[4];
    const float* reg_w  = (const float*)d_in[5];
    const float* reg_b  = (const float*)d_in[6];
    float* out = (float*)d_out;
    char* ws = (char*)d_ws;
    unsigned short* wAf   = (unsigned short*)(ws);
    unsigned short* hwp   = (unsigned short*)(ws + 1572864);
    unsigned short* featT = (unsigned short*)(ws + 1605632);
    float* part           = (float*)(ws + 35225600);

    prep_transpose_kernel<<<dim3(7440), dim3(256), 0, stream>>>(
        feat, conv_w, obj_w, reg_w, wAf, hwp, featT, out);
    conv_gemm_kernel<<<dim3(64, 4, 4), dim3(256), 0, stream>>>(wAf, featT, conv_b, hwp, part);
    reduce_kernel<<<dim3(2304), dim3(256), 0, stream>>>(part, obj_b, reg_b, out);
}

// Round 3
// 173.878 us; speedup vs baseline: 1.5826x; 1.5826x over previous
//
#include <hip/hip_runtime.h>
#include <stdint.h>

typedef __attribute__((ext_vector_type(8))) short short8;
typedef __attribute__((ext_vector_type(4))) float f32x4;
typedef __attribute__((ext_vector_type(4))) float float4v;
typedef __attribute__((ext_vector_type(2))) unsigned short u16x2;
typedef __attribute__((ext_vector_type(4))) unsigned short u16x4;
typedef __attribute__((ext_vector_type(8))) unsigned short u16x8;

#define AS1 __attribute__((address_space(1)))
#define AS3 __attribute__((address_space(3)))

// B=4, C=512, Lf=8192, A=6. N = 49152.
// d_out: obj [4][49152] @0, reg [4][49152][2] @196608, anchors [49152][2] @589824.
// ws layout (bytes):
//   wAf   @ 0        : bf16 pre-fragmented conv weights, chunk id =
//                      (cb*3+t)*16+kc, 512 elems/chunk, lane i of chunk holds
//                      A[cout=cb*16+(i&15)][cin=kc*32+(i>>4)*8 .. +8]  (1,572,864)
//   hwp   @ 1572864  : bf16 [32][512], rows 0-5 obj_w, 6-17 reg_w, rest 0 (32,768)
//   featT @ 1605632  : bf16 [4][8208][512], row r holds l=r-1;
//                      rows 0 and 8193 zeroed (SAME pad), 8194+ slop (33,619,968)
// out is bias-pre-inited by prep; conv heads atomicAdd into it (no reduce pass).

__device__ __forceinline__ unsigned short f2bf(float f) {
    union { float f; unsigned int u; } v; v.f = f;
    unsigned int r = v.u + 0x7fffu + ((v.u >> 16) & 1u);
    return (unsigned short)(r >> 16);
}

__constant__ float c_AL[6] = {2.f, 4.f, 6.f, 9.f, 13.f, 18.f};

// blocks [0,4096): 64x64 transpose tiles.  blocks [4096,9744): prep work
// (weights repack, anchors, pad rows, out bias pre-init).
// Transpose tile is [c][l] stride 66: writes are u16x2 (free), reads are
// paired ds_read_b32 (lane gets l,l+1 of one c) hitting all 32 banks
// (bank = 8*(c8%4)+j+lp, 2-way = free), then register repack to u16x8 rows.
__global__ __launch_bounds__(256) void prep_transpose_kernel(
    const float* __restrict__ feat, const float* __restrict__ conv_w,
    const float* __restrict__ obj_w, const float* __restrict__ reg_w,
    const float* __restrict__ obj_b, const float* __restrict__ reg_b,
    unsigned short* __restrict__ wAf, unsigned short* __restrict__ hwp,
    unsigned short* __restrict__ featT, float* __restrict__ out) {
    __shared__ unsigned short tile[64][66];   // bf16 [c][l], stride 66
    unsigned int bx = blockIdx.x;
    int tid = threadIdx.x;
    if (bx < 4096u) {
        int l0 = (bx & 127) * 64, c0 = ((bx >> 7) & 7) * 64, b = bx >> 10;
        const float* fb = feat + ((size_t)b * 512 + c0) * 8192 + l0;
        #pragma unroll
        for (int it = 0; it < 4; ++it) {
            int slot = it * 256 + tid;
            int c = slot >> 4, l4 = (slot & 15) << 2;
            float4v v = *(const float4v*)(fb + (size_t)c * 8192 + l4);
            u16x2 p0, p1;
            p0.x = f2bf(v.x); p0.y = f2bf(v.y);
            p1.x = f2bf(v.z); p1.y = f2bf(v.w);
            *(u16x2*)(&tile[c][l4])     = p0;
            *(u16x2*)(&tile[c][l4 + 2]) = p1;
        }
        __syncthreads();
        unsigned short* ftb = featT + ((size_t)b * 8208 + 1 + l0) * 512 + c0;
        int c8 = tid & 7, lp = tid >> 3;          // c-chunk 0..7, l-pair 0..31
        unsigned int w[8];
        #pragma unroll
        for (int j = 0; j < 8; ++j)
            w[j] = *(const unsigned int*)(&tile[c8 * 8 + j][lp * 2]);
        u16x8 lo, hi;
        #pragma unroll
        for (int d = 0; d < 4; ++d) {
            unsigned int a = w[2 * d], bb = w[2 * d + 1];
            ((unsigned int*)&lo)[d] = (a & 0xffffu) | (bb << 16);
            ((unsigned int*)&hi)[d] = (a >> 16) | (bb & 0xffff0000u);
        }
        *(u16x8*)(ftb + (size_t)(lp * 2) * 512 + c8 * 8)     = lo;
        *(u16x8*)(ftb + (size_t)(lp * 2 + 1) * 512 + c8 * 8) = hi;
        return;
    }
    unsigned int idx = (bx - 4096u) * 256 + tid;
    if (idx < 786432u) {
        // fragment-major conv weights
        unsigned int chunkid = idx >> 9;            // 0..1535
        unsigned int within = idx & 511u;
        unsigned int lane = within >> 3, j = within & 7u;
        unsigned int kc = chunkid & 15u;
        unsigned int ct = chunkid >> 4;             // cb*3 + t
        unsigned int t = ct % 3u, cb = ct / 3u;
        unsigned int cout = cb * 16u + (lane & 15u);
        unsigned int cin = kc * 32u + (lane >> 4) * 8u + j;
        wAf[idx] = f2bf(conv_w[(cout * 512u + cin) * 3u + t]);
    } else if (idx < 802816u) {
        unsigned int i2 = idx - 786432u;
        unsigned int j = i2 >> 9, c = i2 & 511u;
        float v = 0.f;
        if (j < 6u) v = obj_w[j * 512u + c];
        else if (j < 18u) v = reg_w[(j - 6u) * 512u + c];
        hwp[i2] = f2bf(v);
    } else if (idx < 851968u) {
        unsigned int n = idx - 802816u;
        unsigned int l = n / 6u, a = n - l * 6u;
        float ctr = (float)l + 0.5f, half = 0.5f * c_AL[a];
        float* anchors = out + 589824;
        anchors[2 * n]     = ctr - half;
        anchors[2 * n + 1] = ctr + half;
    } else if (idx < 856064u) {
        unsigned int i4 = idx - 851968u;
        unsigned int b = i4 >> 10, rem = i4 & 1023u;
        unsigned int row = (rem >> 9) ? 8193u : 0u;
        unsigned int c = rem & 511u;
        featT[((size_t)b * 8208 + row) * 512 + c] = 0;
    } else if (idx < 1052672u) {
        // obj bias pre-init: out[i] = obj_b[i % 6]  (49152 % 6 == 0)
        unsigned int i5 = idx - 856064u;
        out[i5] = obj_b[i5 % 6u];
    } else {                                        // idx < 1445888
        // reg bias pre-init: out[196608 + i] = reg_b[i % 12]
        unsigned int i6 = idx - 1052672u;
        out[196608u + i6] = reg_b[i6 % 12u];
    }
}

// Conv GEMM (proven 56.6us structure — do not restage per phase: the
// per-kc bulk staging + 2 barriers is also the L2-locality mechanism;
// splitting it collapsed L2 reuse, FETCH 25MB -> 322MB).
// Per block, 128 couts x 128 l's, K = 3 taps * 512 cin.
// Fragment-major LDS for A and B: every ds_read_b128 is base + lane*16B
// (conflict-free). Epilogue: bias+relu -> bf16 htile in LDS, fused heads
// mini-GEMM -> atomicAdd into bias-pre-inited out (replaces partials+reduce).
// launch_bounds(256,4): 4 blocks/CU resident (LDS 4*34816=139KB<=160KB),
// grid 1024 = exactly 4/CU -> single round, no straggler tail.
__global__ __launch_bounds__(256, 4) void conv_gemm_kernel(
    const unsigned short* __restrict__ wAf,
    const unsigned short* __restrict__ featT,
    const float* __restrict__ conv_b,
    const unsigned short* __restrict__ hwp,
    float* __restrict__ out) {
    __shared__ unsigned short smem[17408];  // loop: 33*512 staging; epi: htile 128*136

    const int tid = threadIdx.x;
    const int wave = tid >> 6, lane = tid & 63;
    const int lq = lane >> 4, lr = lane & 15;
    const int l0 = blockIdx.x * 128;
    const int m0 = blockIdx.y * 128;
    const int b = blockIdx.z;
    const int wm = wave >> 1, wn = wave & 1;
    const unsigned short* ftb = featT + (size_t)b * 8208 * 512;

    f32x4 acc[4][4];
    #pragma unroll
    for (int i = 0; i < 4; ++i)
        #pragma unroll
        for (int j = 0; j < 4; ++j)
            acc[i][j] = (f32x4){0.f, 0.f, 0.f, 0.f};

    for (int kc = 0; kc < 16; ++kc) {
        __syncthreads();
        // 33 chunks of 1024B: 24 A-chunks (fragment-major wAf) + 9 B-chunks
        for (int ci = wave; ci < 33; ci += 4) {
            const unsigned short* g;
            if (ci < 24) {
                int t = ci >> 3, rb = ci & 7;
                g = wAf + ((size_t)(((m0 >> 4) + rb) * 3 + t) * 16 + kc) * 512 + lane * 8;
            } else {
                int lb = ci - 24;
                g = ftb + (size_t)(l0 + lb * 16 + lr) * 512 + kc * 32 + lq * 8;
            }
            __builtin_amdgcn_global_load_lds((const AS1 void*)g,
                                             (AS3 void*)(smem + ci * 512), 16, 0, 0);
        }
        __syncthreads();
        #pragma unroll
        for (int t = 0; t < 3; ++t) {
            short8 af[4], bf[4];
            #pragma unroll
            for (int fm = 0; fm < 4; ++fm)
                af[fm] = *(const short8*)(smem + ((t * 8 + wm * 4 + fm) << 9) + (lane << 3));
            #pragma unroll
            for (int fn = 0; fn < 4; ++fn) {
                int R = wn * 64 + fn * 16 + lr + t;   // tap-shifted B row
                bf[fn] = *(const short8*)(smem + ((24 + (R >> 4)) << 9) +
                                          ((((lq << 4) | (R & 15))) << 3));
            }
            #pragma unroll
            for (int fm = 0; fm < 4; ++fm)
                #pragma unroll
                for (int fn = 0; fn < 4; ++fn)
                    acc[fm][fn] = __builtin_amdgcn_mfma_f32_16x16x32_bf16(
                        af[fm], bf[fn], acc[fm][fn], 0, 0, 0);
        }
    }
    __syncthreads();
    // epilogue 1: bias + relu -> bf16 htile [l=n][c=cout], row stride 136
    #pragma unroll
    for (int fm = 0; fm < 4; ++fm) {
        int mb = wm * 64 + fm * 16 + lq * 4;
        float cb0 = conv_b[m0 + mb];
        float cb1 = conv_b[m0 + mb + 1];
        float cb2 = conv_b[m0 + mb + 2];
        float cb3 = conv_b[m0 + mb + 3];
        #pragma unroll
        for (int fn = 0; fn < 4; ++fn) {
            int n = wn * 64 + fn * 16 + lr;
            f32x4 v = acc[fm][fn];
            u16x4 pk;
            pk.x = f2bf(fmaxf(v.x + cb0, 0.f));
            pk.y = f2bf(fmaxf(v.y + cb1, 0.f));
            pk.z = f2bf(fmaxf(v.z + cb2, 0.f));
            pk.w = f2bf(fmaxf(v.w + cb3, 0.f));
            *(u16x4*)(smem + n * 136 + mb) = pk;
        }
    }
    __syncthreads();
    // epilogue 2: fused heads. Per wave: 32 l's x 32 j's x K=128 local couts.
    f32x4 hacc[2][2];
    #pragma unroll
    for (int i = 0; i < 2; ++i) {
        hacc[i][0] = (f32x4){0.f, 0.f, 0.f, 0.f};
        hacc[i][1] = (f32x4){0.f, 0.f, 0.f, 0.f};
    }
    const int lbase = wave * 32;
    for (int kk = 0; kk < 4; ++kk) {
        short8 ha[2], hb2[2];
        #pragma unroll
        for (int fm2 = 0; fm2 < 2; ++fm2)
            ha[fm2] = *(const short8*)(smem + (lbase + fm2 * 16 + lr) * 136 + kk * 32 + lq * 8);
        #pragma unroll
        for (int fn = 0; fn < 2; ++fn)
            hb2[fn] = *(const short8*)(hwp + (size_t)(fn * 16 + lr) * 512 + m0 + kk * 32 + lq * 8);
        #pragma unroll
        for (int fm2 = 0; fm2 < 2; ++fm2)
            #pragma unroll
            for (int fn = 0; fn < 2; ++fn)
                hacc[fm2][fn] = __builtin_amdgcn_mfma_f32_16x16x32_bf16(
                    ha[fm2], hb2[fn], hacc[fm2][fn], 0, 0, 0);
    }
    // atomic accumulate into bias-pre-inited out (4 m-blocks per address)
    float* ob = out + (size_t)b * 49152;
    float* rg = out + 196608 + (size_t)b * 98304;
    #pragma unroll
    for (int fn = 0; fn < 2; ++fn) {
        int j = fn * 16 + lr;
        if (j >= 18) continue;
        #pragma unroll
        for (int fm2 = 0; fm2 < 2; ++fm2)
            #pragma unroll
            for (int r = 0; r < 4; ++r) {
                int l = l0 + lbase + fm2 * 16 + lq * 4 + r;
                float v = hacc[fm2][fn][r];
                if (j < 6) atomicAdd(ob + (size_t)l * 6 + j, v);
                else       atomicAdd(rg + (size_t)l * 12 + (j - 6), v);
            }
    }
}

extern "C" void kernel_launch(void* const* d_in, const int* in_sizes, int n_in,
                              void* d_out, int out_size, void* d_ws, size_t ws_size,
                              hipStream_t stream) {
    const float* feat   = (const float*)d_in[0];
    const float* conv_w = (const float*)d_in[1];
    const float* conv_b = (const float*)d_in[2];
    const float* obj_w  = (const float*)d_in[3];
    const float* obj_b  = (const float*)d_in[4];
    const float* reg_w  = (const float*)d_in[5];
    const float* reg_b  = (const float*)d_in[6];
    float* out = (float*)d_out;
    char* ws = (char*)d_ws;
    unsigned short* wAf   = (unsigned short*)(ws);
    unsigned short* hwp   = (unsigned short*)(ws + 1572864);
    unsigned short* featT = (unsigned short*)(ws + 1605632);

    prep_transpose_kernel<<<dim3(9744), dim3(256), 0, stream>>>(
        feat, conv_w, obj_w, reg_w, obj_b, reg_b, wAf, hwp, featT, out);
    conv_gemm_kernel<<<dim3(64, 4, 4), dim3(256), 0, stream>>>(
        wAf, featT, conv_b, hwp, out);
}

// Round 4
// 164.456 us; speedup vs baseline: 1.6733x; 1.0573x over previous
//
#include <hip/hip_runtime.h>
#include <stdint.h>

typedef __attribute__((ext_vector_type(8))) short short8;
typedef __attribute__((ext_vector_type(4))) float f32x4;
typedef __attribute__((ext_vector_type(4))) float float4v;
typedef __attribute__((ext_vector_type(2))) unsigned short u16x2;
typedef __attribute__((ext_vector_type(4))) unsigned short u16x4;
typedef __attribute__((ext_vector_type(8))) unsigned short u16x8;

#define AS1 __attribute__((address_space(1)))
#define AS3 __attribute__((address_space(3)))

// B=4, C=512, Lf=8192, A=6. N = 49152.
// d_out: obj [4][49152] @0, reg [4][49152][2] @196608, anchors [49152][2] @589824.
// ws layout (bytes):
//   wAf   @ 0        : bf16 pre-fragmented conv weights, chunk id =
//                      (cb*3+t)*16+kc, 512 elems/chunk, lane i of chunk holds
//                      A[cout=cb*16+(i&15)][cin=kc*32+(i>>4)*8 .. +8]  (1,572,864)
//   hwp   @ 1572864  : bf16 [32][512], rows 0-5 obj_w, 6-17 reg_w, rest 0 (32,768)
//   featT @ 1605632  : bf16 [4][8208][512], row r holds l=r-1;
//                      rows 0 and 8193 zeroed (SAME pad), 8194+ slop (33,619,968)
//   part  @ 35225600 : fp32 [4 mblk][4 b][8192 l][18 j] head partials (9,437,184)

__device__ __forceinline__ unsigned short f2bf(float f) {
    union { float f; unsigned int u; } v; v.f = f;
    unsigned int r = v.u + 0x7fffu + ((v.u >> 16) & 1u);
    return (unsigned short)(r >> 16);
}

__constant__ float c_AL[6] = {2.f, 4.f, 6.f, 9.f, 13.f, 18.f};

// blocks [0,4096): 64x64 transpose tiles.  blocks [4096,7440): prep work.
// Transpose tile is [c][l] stride 66: writes are u16x2 (free), reads are
// paired ds_read_b32 (lane gets l,l+1 of one c) hitting all 32 banks
// (bank = 8*(c8%4)+j+lp, 2-way = free), then register repack to u16x8 rows.
__global__ __launch_bounds__(256) void prep_transpose_kernel(
    const float* __restrict__ feat, const float* __restrict__ conv_w,
    const float* __restrict__ obj_w, const float* __restrict__ reg_w,
    unsigned short* __restrict__ wAf, unsigned short* __restrict__ hwp,
    unsigned short* __restrict__ featT, float* __restrict__ out) {
    __shared__ unsigned short tile[64][66];   // bf16 [c][l], stride 66
    unsigned int bx = blockIdx.x;
    int tid = threadIdx.x;
    if (bx < 4096u) {
        int l0 = (bx & 127) * 64, c0 = ((bx >> 7) & 7) * 64, b = bx >> 10;
        const float* fb = feat + ((size_t)b * 512 + c0) * 8192 + l0;
        #pragma unroll
        for (int it = 0; it < 4; ++it) {
            int slot = it * 256 + tid;
            int c = slot >> 4, l4 = (slot & 15) << 2;
            float4v v = *(const float4v*)(fb + (size_t)c * 8192 + l4);
            u16x2 p0, p1;
            p0.x = f2bf(v.x); p0.y = f2bf(v.y);
            p1.x = f2bf(v.z); p1.y = f2bf(v.w);
            *(u16x2*)(&tile[c][l4])     = p0;
            *(u16x2*)(&tile[c][l4 + 2]) = p1;
        }
        __syncthreads();
        unsigned short* ftb = featT + ((size_t)b * 8208 + 1 + l0) * 512 + c0;
        int c8 = tid & 7, lp = tid >> 3;          // c-chunk 0..7, l-pair 0..31
        unsigned int w[8];
        #pragma unroll
        for (int j = 0; j < 8; ++j)
            w[j] = *(const unsigned int*)(&tile[c8 * 8 + j][lp * 2]);
        u16x8 lo, hi;
        #pragma unroll
        for (int d = 0; d < 4; ++d) {
            unsigned int a = w[2 * d], bb = w[2 * d + 1];
            ((unsigned int*)&lo)[d] = (a & 0xffffu) | (bb << 16);
            ((unsigned int*)&hi)[d] = (a >> 16) | (bb & 0xffff0000u);
        }
        *(u16x8*)(ftb + (size_t)(lp * 2) * 512 + c8 * 8)     = lo;
        *(u16x8*)(ftb + (size_t)(lp * 2 + 1) * 512 + c8 * 8) = hi;
        return;
    }
    unsigned int idx = (bx - 4096u) * 256 + tid;
    if (idx < 786432u) {
        // fragment-major conv weights
        unsigned int chunkid = idx >> 9;            // 0..1535
        unsigned int within = idx & 511u;
        unsigned int lane = within >> 3, j = within & 7u;
        unsigned int kc = chunkid & 15u;
        unsigned int ct = chunkid >> 4;             // cb*3 + t
        unsigned int t = ct % 3u, cb = ct / 3u;
        unsigned int cout = cb * 16u + (lane & 15u);
        unsigned int cin = kc * 32u + (lane >> 4) * 8u + j;
        wAf[idx] = f2bf(conv_w[(cout * 512u + cin) * 3u + t]);
    } else if (idx < 802816u) {
        unsigned int i2 = idx - 786432u;
        unsigned int j = i2 >> 9, c = i2 & 511u;
        float v = 0.f;
        if (j < 6u) v = obj_w[j * 512u + c];
        else if (j < 18u) v = reg_w[(j - 6u) * 512u + c];
        hwp[i2] = f2bf(v);
    } else if (idx < 851968u) {
        unsigned int n = idx - 802816u;
        unsigned int l = n / 6u, a = n - l * 6u;
        float ctr = (float)l + 0.5f, half = 0.5f * c_AL[a];
        float* anchors = out + 589824;
        anchors[2 * n]     = ctr - half;
        anchors[2 * n + 1] = ctr + half;
    } else if (idx < 856064u) {
        unsigned int i4 = idx - 851968u;
        unsigned int b = i4 >> 10, rem = i4 & 1023u;
        unsigned int row = (rem >> 9) ? 8193u : 0u;
        unsigned int c = rem & 511u;
        featT[((size_t)b * 8208 + row) * 512 + c] = 0;
    }
}

// Conv GEMM, deep-pipelined port of the proven fragment layouts.
// Tile: 128 couts x 256 l's, 8 waves (2m x 4n), wave tile 64x64.
// K: 16 steps of 32 cin, each step = 3 tap-phases of 16 MFMA.
// LDS: 3-slot ring, slot = 41 chunks x 1KB (24 A fragment chunks [t][rb]
// + 17 B chunks, 272 feat rows incl. halo).  During step kc each wave
// issues its 5 (wave0: 6) global_load_lds chunks for step kc+2 into slot
// (kc+2)%3; at each step boundary it waits s_waitcnt vmcnt(5/6) — its own
// in-flight count for kc+2 — so next-step loads are NEVER drained (T4).
// Raw s_barrier everywhere (no implicit vmcnt(0) drain); single vmcnt(0)
// only at kc=15.  setprio around each 16-MFMA cluster (T5).  All
// ds_read_b128 patterns are byte-identical to the proven conflict-free
// fragment-major ones.  Grid 512 = 1 block/CU x 2 rounds; B-panel sharers
// (same bx) are 32 apart => same XCD => L2-served re-reads (~2.5MB/XCD).
// Epilogue: bias+relu -> bf16 htile [256][136], fused heads mini-GEMM ->
// per-mblock partials (atomics measured -19us in R3: do not use).
__global__ __launch_bounds__(512, 1) void conv_gemm_kernel(
    const unsigned short* __restrict__ wAf,
    const unsigned short* __restrict__ featT,
    const float* __restrict__ conv_b,
    const unsigned short* __restrict__ hwp,
    float* __restrict__ part) {
    extern __shared__ __align__(16) unsigned short smem[];  // 3*20992 shorts

    const int tid = threadIdx.x;
    const int wave = tid >> 6, lane = tid & 63;
    const int lq = lane >> 4, lr = lane & 15;
    const int wm = wave >> 2, wn = wave & 3;   // 2 m-waves x 4 n-waves
    const int l0 = blockIdx.x * 256;
    const int my = blockIdx.y;                 // m0 = my*128
    const int m0 = my * 128;
    const int b = blockIdx.z;
    const unsigned short* ftb = featT + (size_t)b * 8208 * 512;

    // chunk ci in [0,41): ci<24 -> A(t=ci>>3, rb=ci&7); else B cb=ci-24.
    auto stage = [&](int ci, int kc, int slot) {
        const unsigned short* g;
        if (ci < 24) {
            int t = ci >> 3, rb = ci & 7;
            g = wAf + ((size_t)(((my * 8 + rb) * 3 + t) * 16 + kc)) * 512 + lane * 8;
        } else {
            int cb = ci - 24;
            g = ftb + (size_t)(l0 + cb * 16 + lr) * 512 + kc * 32 + lq * 8;
        }
        __builtin_amdgcn_global_load_lds((const AS1 void*)g,
                                         (AS3 void*)(smem + slot * 20992 + ci * 512),
                                         16, 0, 0);
    };

    f32x4 acc[4][4];
    #pragma unroll
    for (int i = 0; i < 4; ++i)
        #pragma unroll
        for (int j = 0; j < 4; ++j)
            acc[i][j] = (f32x4){0.f, 0.f, 0.f, 0.f};

    // prologue: stage steps 0 and 1 into slots 0,1; wait only for step 0
    // (step 1's loads remain in flight across the barrier).
    #pragma unroll
    for (int k = 0; k < 5; ++k) stage(wave + k * 8, 0, 0);
    if (wave == 0) stage(40, 0, 0);
    #pragma unroll
    for (int k = 0; k < 5; ++k) stage(wave + k * 8, 1, 1);
    if (wave == 0) stage(40, 1, 1);
    if (wave == 0) asm volatile("s_waitcnt vmcnt(6)" ::: "memory");
    else           asm volatile("s_waitcnt vmcnt(5)" ::: "memory");
    __builtin_amdgcn_s_barrier();

    for (int kc = 0; kc < 16; ++kc) {
        unsigned short* cur = smem + (kc % 3) * 20992;
        const int nslot = (kc + 2) % 3;
        #pragma unroll
        for (int t = 0; t < 3; ++t) {
            short8 af[4], bf[4];
            #pragma unroll
            for (int fm = 0; fm < 4; ++fm)
                af[fm] = *(const short8*)(cur + ((t * 8 + wm * 4 + fm) << 9) + (lane << 3));
            #pragma unroll
            for (int fn = 0; fn < 4; ++fn) {
                int R = wn * 64 + fn * 16 + lr + t;   // tap-shifted B row
                bf[fn] = *(const short8*)(cur + ((24 + (R >> 4)) << 9) +
                                          (((lq << 4) | (R & 15)) << 3));
            }
            // issue prefetch for step kc+2 (2,2,1(+1) chunks per phase)
            if (kc < 14) {
                if (t < 2) {
                    stage(wave + (2 * t) * 8, kc + 2, nslot);
                    stage(wave + (2 * t + 1) * 8, kc + 2, nslot);
                } else {
                    stage(wave + 32, kc + 2, nslot);
                    if (wave == 0) stage(40, kc + 2, nslot);
                }
            }
            asm volatile("s_waitcnt lgkmcnt(0)" ::: "memory");
            __builtin_amdgcn_sched_barrier(0);
            __builtin_amdgcn_s_setprio(1);
            #pragma unroll
            for (int fm = 0; fm < 4; ++fm)
                #pragma unroll
                for (int fn = 0; fn < 4; ++fn)
                    acc[fm][fn] = __builtin_amdgcn_mfma_f32_16x16x32_bf16(
                        af[fm], bf[fn], acc[fm][fn], 0, 0, 0);
            __builtin_amdgcn_s_setprio(0);
            __builtin_amdgcn_s_barrier();
            asm volatile("" ::: "memory");
        }
        // step boundary: ensure step kc+1's data landed; kc+2's stay in flight.
        if (kc < 14) {
            if (wave == 0) asm volatile("s_waitcnt vmcnt(6)" ::: "memory");
            else           asm volatile("s_waitcnt vmcnt(5)" ::: "memory");
            __builtin_amdgcn_s_barrier();
            asm volatile("" ::: "memory");
        } else if (kc == 14) {
            asm volatile("s_waitcnt vmcnt(0)" ::: "memory");
            __builtin_amdgcn_s_barrier();
            asm volatile("" ::: "memory");
        }
    }
    __syncthreads();
    // epilogue 1: bias + relu -> bf16 htile [l=n][c=cout], row stride 136
    #pragma unroll
    for (int fm = 0; fm < 4; ++fm) {
        int mb = wm * 64 + fm * 16 + lq * 4;
        float cb0 = conv_b[m0 + mb];
        float cb1 = conv_b[m0 + mb + 1];
        float cb2 = conv_b[m0 + mb + 2];
        float cb3 = conv_b[m0 + mb + 3];
        #pragma unroll
        for (int fn = 0; fn < 4; ++fn) {
            int n = wn * 64 + fn * 16 + lr;
            f32x4 v = acc[fm][fn];
            u16x4 pk;
            pk.x = f2bf(fmaxf(v.x + cb0, 0.f));
            pk.y = f2bf(fmaxf(v.y + cb1, 0.f));
            pk.z = f2bf(fmaxf(v.z + cb2, 0.f));
            pk.w = f2bf(fmaxf(v.w + cb3, 0.f));
            *(u16x4*)(smem + n * 136 + mb) = pk;
        }
    }
    __syncthreads();
    // epilogue 2: fused heads. Per wave: 32 l's x 32 j's x K=128 local couts.
    f32x4 hacc[2][2];
    #pragma unroll
    for (int i = 0; i < 2; ++i) {
        hacc[i][0] = (f32x4){0.f, 0.f, 0.f, 0.f};
        hacc[i][1] = (f32x4){0.f, 0.f, 0.f, 0.f};
    }
    const int lbase = wave * 32;
    for (int kk = 0; kk < 4; ++kk) {
        short8 ha[2], hb2[2];
        #pragma unroll
        for (int fm2 = 0; fm2 < 2; ++fm2)
            ha[fm2] = *(const short8*)(smem + (lbase + fm2 * 16 + lr) * 136 + kk * 32 + lq * 8);
        #pragma unroll
        for (int fn = 0; fn < 2; ++fn)
            hb2[fn] = *(const short8*)(hwp + (size_t)(fn * 16 + lr) * 512 + m0 + kk * 32 + lq * 8);
        #pragma unroll
        for (int fm2 = 0; fm2 < 2; ++fm2)
            #pragma unroll
            for (int fn = 0; fn < 2; ++fn)
                hacc[fm2][fn] = __builtin_amdgcn_mfma_f32_16x16x32_bf16(
                    ha[fm2], hb2[fn], hacc[fm2][fn], 0, 0, 0);
    }
    // partials store: part[mblk=my][b][l][j]
    float* pb = part + ((size_t)(my * 4 + b) * 8192) * 18;
    #pragma unroll
    for (int fn = 0; fn < 2; ++fn) {
        int j = fn * 16 + lr;
        if (j >= 18) continue;
        #pragma unroll
        for (int fm2 = 0; fm2 < 2; ++fm2)
            #pragma unroll
            for (int r = 0; r < 4; ++r) {
                int l = l0 + lbase + fm2 * 16 + lq * 4 + r;
                pb[(size_t)l * 18 + j] = hacc[fm2][fn][r];
            }
    }
}

__global__ __launch_bounds__(256) void reduce_kernel(
    const float* __restrict__ part, const float* __restrict__ obj_b,
    const float* __restrict__ reg_b, float* __restrict__ out) {
    unsigned int idx = blockIdx.x * 256 + threadIdx.x;
    if (idx >= 589824u) return;
    unsigned int j = idx % 18u;
    unsigned int t = idx / 18u;
    unsigned int l = t & 8191u;
    unsigned int b = t >> 13;
    float s = 0.f;
    #pragma unroll
    for (int mb = 0; mb < 4; ++mb)
        s += part[((size_t)(mb * 4 + b) * 8192 + l) * 18 + j];
    if (j < 6u) {
        s += obj_b[j];
        out[(size_t)b * 49152 + l * 6 + j] = s;
    } else {
        s += reg_b[j - 6u];
        out[196608u + (size_t)b * 98304 + l * 12 + (j - 6u)] = s;
    }
}

extern "C" void kernel_launch(void* const* d_in, const int* in_sizes, int n_in,
                              void* d_out, int out_size, void* d_ws, size_t ws_size,
                              hipStream_t stream) {
    const float* feat   = (const float*)d_in[0];
    const float* conv_w = (const float*)d_in[1];
    const float* conv_b = (const float*)d_in[2];
    const float* obj_w  = (const float*)d_in[3];
    const float* obj_b  = (const float*)d_in[4];
    const float* reg_w  = (const float*)d_in[5];
    const float* reg_b  = (const float*)d_in[6];
    float* out = (float*)d_out;
    char* ws = (char*)d_ws;
    unsigned short* wAf   = (unsigned short*)(ws);
    unsigned short* hwp   = (unsigned short*)(ws + 1572864);
    unsigned short* featT = (unsigned short*)(ws + 1605632);
    float* part           = (float*)(ws + 35225600);

    static bool attr_done = false;
    if (!attr_done) {
        hipFuncSetAttribute(reinterpret_cast<const void*>(conv_gemm_kernel),
                            hipFuncAttributeMaxDynamicSharedMemorySize, 125952);
        attr_done = true;
    }

    prep_transpose_kernel<<<dim3(7440), dim3(256), 0, stream>>>(
        feat, conv_w, obj_w, reg_w, wAf, hwp, featT, out);
    conv_gemm_kernel<<<dim3(32, 4, 4), dim3(512), 125952, stream>>>(
        wAf, featT, conv_b, hwp, part);
    reduce_kernel<<<dim3(2304), dim3(256), 0, stream>>>(part, obj_b, reg_b, out);
}

// Round 5
// 162.946 us; speedup vs baseline: 1.6888x; 1.0093x over previous
//
#include <hip/hip_runtime.h>
#include <stdint.h>

typedef __attribute__((ext_vector_type(8))) short short8;
typedef __attribute__((ext_vector_type(4))) float f32x4;
typedef __attribute__((ext_vector_type(4))) float float4v;
typedef __attribute__((ext_vector_type(2))) unsigned short u16x2;
typedef __attribute__((ext_vector_type(4))) unsigned short u16x4;
typedef __attribute__((ext_vector_type(8))) unsigned short u16x8;

#define AS1 __attribute__((address_space(1)))
#define AS3 __attribute__((address_space(3)))

// B=4, C=512, Lf=8192, A=6. N = 49152.
// d_out: obj [4][49152] @0, reg [4][49152][2] @196608, anchors [49152][2] @589824.
// ws layout (bytes):
//   wAf   @ 0        : bf16 pre-fragmented conv weights, chunk id =
//                      (cb*3+t)*16+kc, 512 elems/chunk, lane i of chunk holds
//                      A[cout=cb*16+(i&15)][cin=kc*32+(i>>4)*8 .. +8]  (1,572,864)
//   hwp   @ 1572864  : bf16 [32][512], rows 0-5 obj_w, 6-17 reg_w, rest 0 (32,768)
//   featT @ 1605632  : bf16 [4][8208][512], row r holds l=r-1;
//                      rows 0 and 8193 zeroed (SAME pad), 8194+ slop (33,619,968)
//   part  @ 35225600 : fp32 [4 mblk][4 b][8192 l][18 j] head partials (9,437,184)
//
// Session ledger (measured):
//   conv 2-barrier 128^2 4blk/CU: 56.6us, MfmaUtil 38.7 — champion, keep.
//   conv 256^2 1blk/CU 8-phase:   85.8us (bank conflicts + occupancy loss)
//   conv per-phase restage:      162.4us (L2 reuse collapse, FETCH 25->322MB)
//   conv 3-slot ring 1blk/CU:     60.4us (latency-exposed at 2 waves/SIMD)
//   atomic epilogue:             +18.8us vs partials+reduce — do not use.

__device__ __forceinline__ unsigned short f2bf(float f) {
    union { float f; unsigned int u; } v; v.f = f;
    unsigned int r = v.u + 0x7fffu + ((v.u >> 16) & 1u);
    return (unsigned short)(r >> 16);
}

__constant__ float c_AL[6] = {2.f, 4.f, 6.f, 9.f, 13.f, 18.f};

// blocks [0,4096): 64x64 transpose tiles.  blocks [4096,5136): prep tail
// (vectorized weight repack, head weights, anchors, pad rows).
// Transpose tile is [c][l] stride 66: writes are u16x2 (free), reads are
// paired ds_read_b32 (lane gets l,l+1 of one c) hitting all 32 banks
// (bank = 8*(c8%4)+j+lp, 2-way = free), then register repack to u16x8 rows.
__global__ __launch_bounds__(256) void prep_transpose_kernel(
    const float* __restrict__ feat, const float* __restrict__ conv_w,
    const float* __restrict__ obj_w, const float* __restrict__ reg_w,
    unsigned short* __restrict__ wAf, unsigned short* __restrict__ hwp,
    unsigned short* __restrict__ featT, float* __restrict__ out) {
    __shared__ unsigned short tile[64][66];   // bf16 [c][l], stride 66
    unsigned int bx = blockIdx.x;
    int tid = threadIdx.x;
    if (bx < 4096u) {
        int l0 = (bx & 127) * 64, c0 = ((bx >> 7) & 7) * 64, b = bx >> 10;
        const float* fb = feat + ((size_t)b * 512 + c0) * 8192 + l0;
        #pragma unroll
        for (int it = 0; it < 4; ++it) {
            int slot = it * 256 + tid;
            int c = slot >> 4, l4 = (slot & 15) << 2;
            float4v v = *(const float4v*)(fb + (size_t)c * 8192 + l4);
            u16x2 p0, p1;
            p0.x = f2bf(v.x); p0.y = f2bf(v.y);
            p1.x = f2bf(v.z); p1.y = f2bf(v.w);
            *(u16x2*)(&tile[c][l4])     = p0;
            *(u16x2*)(&tile[c][l4 + 2]) = p1;
        }
        __syncthreads();
        unsigned short* ftb = featT + ((size_t)b * 8208 + 1 + l0) * 512 + c0;
        int c8 = tid & 7, lp = tid >> 3;          // c-chunk 0..7, l-pair 0..31
        unsigned int w[8];
        #pragma unroll
        for (int j = 0; j < 8; ++j)
            w[j] = *(const unsigned int*)(&tile[c8 * 8 + j][lp * 2]);
        u16x8 lo, hi;
        #pragma unroll
        for (int d = 0; d < 4; ++d) {
            unsigned int a = w[2 * d], bb = w[2 * d + 1];
            ((unsigned int*)&lo)[d] = (a & 0xffffu) | (bb << 16);
            ((unsigned int*)&hi)[d] = (a >> 16) | (bb & 0xffff0000u);
        }
        *(u16x8*)(ftb + (size_t)(lp * 2) * 512 + c8 * 8)     = lo;
        *(u16x8*)(ftb + (size_t)(lp * 2 + 1) * 512 + c8 * 8) = hi;
        return;
    }
    unsigned int idx = (bx - 4096u) * 256 + tid;
    if (idx < 196608u) {
        // fragment-major conv weights, 4 consecutive elems/thread
        // (same lane, same cout, cin0..cin0+3; u16x4 store)
        unsigned int base = idx * 4u;
        unsigned int chunkid = base >> 9;           // 0..1535
        unsigned int within = base & 511u;
        unsigned int lane = within >> 3, j0 = within & 7u;   // j0 in {0,4}
        unsigned int kc = chunkid & 15u;
        unsigned int ct = chunkid >> 4;             // cb*3 + t
        unsigned int t = ct % 3u, cb = ct / 3u;
        unsigned int cout = cb * 16u + (lane & 15u);
        unsigned int cin0 = kc * 32u + (lane >> 4) * 8u + j0;
        const float* src = conv_w + (size_t)(cout * 512u + cin0) * 3u + t;
        u16x4 pk;
        pk.x = f2bf(src[0]);
        pk.y = f2bf(src[3]);
        pk.z = f2bf(src[6]);
        pk.w = f2bf(src[9]);
        *(u16x4*)(wAf + base) = pk;
    } else if (idx < 212992u) {
        unsigned int i2 = idx - 196608u;
        unsigned int j = i2 >> 9, c = i2 & 511u;
        float v = 0.f;
        if (j < 6u) v = obj_w[j * 512u + c];
        else if (j < 18u) v = reg_w[(j - 6u) * 512u + c];
        hwp[i2] = f2bf(v);
    } else if (idx < 262144u) {
        unsigned int n = idx - 212992u;
        unsigned int l = n / 6u, a = n - l * 6u;
        float ctr = (float)l + 0.5f, half = 0.5f * c_AL[a];
        float* anchors = out + 589824;
        anchors[2 * n]     = ctr - half;
        anchors[2 * n + 1] = ctr + half;
    } else if (idx < 266240u) {
        unsigned int i4 = idx - 262144u;
        unsigned int b = i4 >> 10, rem = i4 & 1023u;
        unsigned int row = (rem >> 9) ? 8193u : 0u;
        unsigned int c = rem & 511u;
        featT[((size_t)b * 8208 + row) * 512 + c] = 0;
    }
}

// Conv GEMM (proven 56.6us champion — measured best of 4 structures, see
// ledger above).  Per block, 128 couts x 128 l's, K = 3 taps * 512 cin.
// Fragment-major LDS for A and B: every ds_read_b128 is base + lane*16B
// (conflict-free). Epilogue: bias+relu -> bf16 htile in LDS, fused heads
// mini-GEMM -> per-mblock partials in ws (atomic-free, reduced later).
// launch_bounds(256,4): 4 blocks/CU resident (LDS 4*34816=139KB<=160KB),
// grid 1024 = exactly 4/CU -> single round, no straggler tail.
__global__ __launch_bounds__(256, 4) void conv_gemm_kernel(
    const unsigned short* __restrict__ wAf,
    const unsigned short* __restrict__ featT,
    const float* __restrict__ conv_b,
    const unsigned short* __restrict__ hwp,
    float* __restrict__ part) {
    __shared__ unsigned short smem[17408];  // loop: 33*512 staging; epi: htile 128*136

    const int tid = threadIdx.x;
    const int wave = tid >> 6, lane = tid & 63;
    const int lq = lane >> 4, lr = lane & 15;
    const int l0 = blockIdx.x * 128;
    const int m0 = blockIdx.y * 128;
    const int b = blockIdx.z;
    const int wm = wave >> 1, wn = wave & 1;
    const unsigned short* ftb = featT + (size_t)b * 8208 * 512;

    f32x4 acc[4][4];
    #pragma unroll
    for (int i = 0; i < 4; ++i)
        #pragma unroll
        for (int j = 0; j < 4; ++j)
            acc[i][j] = (f32x4){0.f, 0.f, 0.f, 0.f};

    for (int kc = 0; kc < 16; ++kc) {
        __syncthreads();
        // 33 chunks of 1024B: 24 A-chunks (fragment-major wAf) + 9 B-chunks
        for (int ci = wave; ci < 33; ci += 4) {
            const unsigned short* g;
            if (ci < 24) {
                int t = ci >> 3, rb = ci & 7;
                g = wAf + ((size_t)(((m0 >> 4) + rb) * 3 + t) * 16 + kc) * 512 + lane * 8;
            } else {
                int lb = ci - 24;
                g = ftb + (size_t)(l0 + lb * 16 + lr) * 512 + kc * 32 + lq * 8;
            }
            __builtin_amdgcn_global_load_lds((const AS1 void*)g,
                                             (AS3 void*)(smem + ci * 512), 16, 0, 0);
        }
        __syncthreads();
        #pragma unroll
        for (int t = 0; t < 3; ++t) {
            short8 af[4], bf[4];
            #pragma unroll
            for (int fm = 0; fm < 4; ++fm)
                af[fm] = *(const short8*)(smem + ((t * 8 + wm * 4 + fm) << 9) + (lane << 3));
            #pragma unroll
            for (int fn = 0; fn < 4; ++fn) {
                int R = wn * 64 + fn * 16 + lr + t;   // tap-shifted B row
                bf[fn] = *(const short8*)(smem + ((24 + (R >> 4)) << 9) +
                                          ((((lq << 4) | (R & 15))) << 3));
            }
            #pragma unroll
            for (int fm = 0; fm < 4; ++fm)
                #pragma unroll
                for (int fn = 0; fn < 4; ++fn)
                    acc[fm][fn] = __builtin_amdgcn_mfma_f32_16x16x32_bf16(
                        af[fm], bf[fn], acc[fm][fn], 0, 0, 0);
        }
    }
    __syncthreads();
    // epilogue 1: bias + relu -> bf16 htile [l=n][c=cout], row stride 136
    #pragma unroll
    for (int fm = 0; fm < 4; ++fm) {
        int mb = wm * 64 + fm * 16 + lq * 4;
        float cb0 = conv_b[m0 + mb];
        float cb1 = conv_b[m0 + mb + 1];
        float cb2 = conv_b[m0 + mb + 2];
        float cb3 = conv_b[m0 + mb + 3];
        #pragma unroll
        for (int fn = 0; fn < 4; ++fn) {
            int n = wn * 64 + fn * 16 + lr;
            f32x4 v = acc[fm][fn];
            u16x4 pk;
            pk.x = f2bf(fmaxf(v.x + cb0, 0.f));
            pk.y = f2bf(fmaxf(v.y + cb1, 0.f));
            pk.z = f2bf(fmaxf(v.z + cb2, 0.f));
            pk.w = f2bf(fmaxf(v.w + cb3, 0.f));
            *(u16x4*)(smem + n * 136 + mb) = pk;
        }
    }
    __syncthreads();
    // epilogue 2: fused heads. Per wave: 32 l's x 32 j's x K=128 local couts.
    f32x4 hacc[2][2];
    #pragma unroll
    for (int i = 0; i < 2; ++i) {
        hacc[i][0] = (f32x4){0.f, 0.f, 0.f, 0.f};
        hacc[i][1] = (f32x4){0.f, 0.f, 0.f, 0.f};
    }
    const int lbase = wave * 32;
    for (int kk = 0; kk < 4; ++kk) {
        short8 ha[2], hb2[2];
        #pragma unroll
        for (int fm2 = 0; fm2 < 2; ++fm2)
            ha[fm2] = *(const short8*)(smem + (lbase + fm2 * 16 + lr) * 136 + kk * 32 + lq * 8);
        #pragma unroll
        for (int fn = 0; fn < 2; ++fn)
            hb2[fn] = *(const short8*)(hwp + (size_t)(fn * 16 + lr) * 512 + m0 + kk * 32 + lq * 8);
        #pragma unroll
        for (int fm2 = 0; fm2 < 2; ++fm2)
            #pragma unroll
            for (int fn = 0; fn < 2; ++fn)
                hacc[fm2][fn] = __builtin_amdgcn_mfma_f32_16x16x32_bf16(
                    ha[fm2], hb2[fn], hacc[fm2][fn], 0, 0, 0);
    }
    // partials store: part[mblk=by][b][l][j]
    float* pb = part + ((size_t)(blockIdx.y * 4 + b) * 8192) * 18;
    #pragma unroll
    for (int fn = 0; fn < 2; ++fn) {
        int j = fn * 16 + lr;
        if (j >= 18) continue;
        #pragma unroll
        for (int fm2 = 0; fm2 < 2; ++fm2)
            #pragma unroll
            for (int r = 0; r < 4; ++r) {
                int l = l0 + lbase + fm2 * 16 + lq * 4 + r;
                pb[(size_t)l * 18 + j] = hacc[fm2][fn][r];
            }
    }
}

// One thread per (b,l): reads 4x 72B contiguous runs (coalesced across the
// wave), writes 24B obj + 48B reg contiguous runs (coalesced) — replaces
// the old j-major variant whose stores were 4B scatter.
__global__ __launch_bounds__(256) void reduce_kernel(
    const float* __restrict__ part, const float* __restrict__ obj_b,
    const float* __restrict__ reg_b, float* __restrict__ out) {
    unsigned int idx = blockIdx.x * 256 + threadIdx.x;   // 32768 = b*8192 + l
    unsigned int l = idx & 8191u, b = idx >> 13;
    float s[18];
    #pragma unroll
    for (int j = 0; j < 18; ++j) s[j] = 0.f;
    #pragma unroll
    for (int mb = 0; mb < 4; ++mb) {
        const float* p = part + ((size_t)(mb * 4 + b) * 8192 + l) * 18;
        #pragma unroll
        for (int j = 0; j < 18; ++j) s[j] += p[j];
    }
    float* ob = out + (size_t)b * 49152 + (size_t)l * 6;
    #pragma unroll
    for (int j = 0; j < 6; ++j) ob[j] = s[j] + obj_b[j];
    float* rg = out + 196608 + (size_t)b * 98304 + (size_t)l * 12;
    #pragma unroll
    for (int j = 0; j < 12; ++j) rg[j] = s[6 + j] + reg_b[j];
}

extern "C" void kernel_launch(void* const* d_in, const int* in_sizes, int n_in,
                              void* d_out, int out_size, void* d_ws, size_t ws_size,
                              hipStream_t stream) {
    const float* feat   = (const float*)d_in[0];
    const float* conv_w = (const float*)d_in[1];
    const float* conv_b = (const float*)d_in[2];
    const float* obj_w  = (const float*)d_in[3];
    const float* obj_b  = (const float*)d_in[4];
    const float* reg_w  = (const float*)d_in[5];
    const float* reg_b  = (const float*)d_in[6];
    float* out = (float*)d_out;
    char* ws = (char*)d_ws;
    unsigned short* wAf   = (unsigned short*)(ws);
    unsigned short* hwp   = (unsigned short*)(ws + 1572864);
    unsigned short* featT = (unsigned short*)(ws + 1605632);
    float* part           = (float*)(ws + 35225600);

    prep_transpose_kernel<<<dim3(5136), dim3(256), 0, stream>>>(
        feat, conv_w, obj_w, reg_w, wAf, hwp, featT, out);
    conv_gemm_kernel<<<dim3(64, 4, 4), dim3(256), 0, stream>>>(wAf, featT, conv_b, hwp, part);
    reduce_kernel<<<dim3(128), dim3(256), 0, stream>>>(part, obj_b, reg_b, out);
}